// Round 4
// baseline (321.550 us; speedup 1.0000x reference)
//
#include <hip/hip_runtime.h>
#include <math.h>

#define TWO_PI 6.28318530717958647692f
#define SCALE_INV_SQRT_D 0.08838834764831844f   // 1/sqrt(128)

#define NQ 65536
#define NV 131072

typedef __attribute__((ext_vector_type(8))) short s16x8;
typedef __attribute__((ext_vector_type(4))) short s16x4;
typedef __attribute__((ext_vector_type(4))) float f32x4;

__device__ __forceinline__ unsigned short f2bf(float f) {
    unsigned int u = __builtin_bit_cast(unsigned int, f);
    u += 0x7fffu + ((u >> 16) & 1u);          // round-to-nearest-even
    return (unsigned short)(u >> 16);
}
__device__ __forceinline__ float bf2f(unsigned short s) {
    return __builtin_bit_cast(float, (unsigned)s << 16);
}
// gfx950 LDS transpose read: lane reads 4 bf16 at (addr + j*32B), j=0..3
__device__ __forceinline__ s16x4 ds_tr16(unsigned addr) {
    s16x4 r;
    asm volatile("ds_read_b64_tr_b16 %0, %1" : "=v"(r) : "v"(addr) : "memory");
    return r;
}
#define LGKM0() asm volatile("s_waitcnt lgkmcnt(0)" ::: "memory")
#define SBAR0() __builtin_amdgcn_sched_barrier(0)

// k-slot permutation induced by tr-read A-fragments:
// slot (g,i) holds k = ks*32 + (i>=4)*16 + g*4 + (i&3); bijective per 32-window.
__device__ __forceinline__ int kperm(int kk) {
    int i = kk & 7, gg = (kk >> 3) & 3, ks = kk >> 5;
    return (ks << 5) + ((i & 4) << 2) + (gg << 2) + (i & 3);
}

// ---------------------------------------------------------------------------
// prep: weights -> bf16, transposed to [N][K]. W2-like matrices (consumed via
// tr-read A-frags) additionally get the k-slot permutation baked in.
// wbuf (ushort): qw1t[32768] qw2tp[32768] vw1t[32768] vw2tp[32768]
//                sewrt[16384] sewetp[16384]
// ---------------------------------------------------------------------------
__global__ __launch_bounds__(256) void prep_kernel(
    const float* __restrict__ qw1, const float* __restrict__ qw2,
    const float* __restrict__ vw1, const float* __restrict__ vw2,
    const float* __restrict__ sewr, const float* __restrict__ sewe,
    unsigned short* __restrict__ wbuf)
{
    int i = blockIdx.x * 256 + threadIdx.x;   // 163840 total
    float v;
    if (i < 32768)        { int li = i;          int n = li >> 7, k = li & 127;          v = qw1[k * 256 + n]; }
    else if (i < 65536)   { int li = i - 32768;  int n = li >> 8, k = kperm(li & 255);   v = qw2[k * 128 + n]; }
    else if (i < 98304)   { int li = i - 65536;  int n = li >> 7, k = li & 127;          v = vw1[k * 256 + n]; }
    else if (i < 131072)  { int li = i - 98304;  int n = li >> 8, k = kperm(li & 255);   v = vw2[k * 128 + n]; }
    else if (i < 147456)  { int li = i - 131072; int n = li >> 7, k = li & 127;          v = sewr[k * 128 + n]; }
    else                  { int li = i - 147456; int n = li >> 7, k = kperm(li & 127);   v = sewe[k * 128 + n]; }
    wbuf[i] = f2bf(v);
}

// ---------------------------------------------------------------------------
// mlp_kernel v2: BARRIER-FREE. 4 waves/block, each wave owns 16 rows
// end-to-end with 8KB wave-private LDS:
//   region A (4KB): g1T [128][16]  ->  pe [16][128] (XOR-swizzled)
//   region B (4KB): featbf [16][128] -> hT halves [128][16]
// GEMM2 split into two k-halves so hT fits in 4KB.
// A-frags: pe/feat via swizzled ds_read_b128; hT/g1T via ds_read_b64_tr_b16
// (k-permutation matched by w2tp/sewetp). No __syncthreads anywhere.
// ---------------------------------------------------------------------------
template<bool GATE>
__global__ __launch_bounds__(256) void mlp_kernel(
    const float* __restrict__ ref_pts,
    const int*   __restrict__ ctr_coor,
    const float* __restrict__ ctr_feat,
    const unsigned short* __restrict__ w1t,   // [256][128]
    const float* __restrict__ b1,
    const unsigned short* __restrict__ w2tp,  // [128][256] k-permuted
    const float* __restrict__ b2,
    const unsigned short* __restrict__ sewrt, // [128][128]
    const float* __restrict__ sebr,
    const unsigned short* __restrict__ sewetp,// [128][128] k-permuted
    const float* __restrict__ sebe,
    unsigned short* __restrict__ outb)        // rows x 128 bf16
{
    __shared__ __attribute__((aligned(16))) char s_lds[32768];
    const int t    = threadIdx.x;
    const int lane = t & 63;
    const int wid  = t >> 6;
    const int r16  = lane & 15;
    const int g    = lane >> 4;
    const int row0w = blockIdx.x * 64 + wid * 16;

    char* regA = s_lds + wid * 8192;
    char* regB = regA + 4096;
    const unsigned bA = (unsigned)(size_t)regA;
    const unsigned bB = (unsigned)(size_t)regB;
    const int swz = (r16 & 7) << 4;

    // ---- coords (per-lane, no LDS)
    float xx, yy;
    if (GATE) {
        xx = ((float)ctr_coor[(row0w + r16) * 3 + 1] + 0.5f) * 0.2f;
        yy = ((float)ctr_coor[(row0w + r16) * 3 + 2] + 0.5f) * 0.2f;
    } else {
        xx = ref_pts[(row0w + r16) * 3 + 1];
        yy = ref_pts[(row0w + r16) * 3 + 2];
    }
    const float px = (xx + 51.2f) * (TWO_PI / 102.4f);
    const float py = (yy + 51.2f) * (TWO_PI / 102.4f);

    f32x4 gacc[8];
    if (GATE) {
        // ---- stage feat -> regB [16][128] bf16 swizzled (coalesced loads)
        #pragma unroll
        for (int it = 0; it < 8; ++it) {
            int row = it * 2 + (lane >> 5);
            int c4  = lane & 31;
            f32x4 v = *(const f32x4*)(ctr_feat + (size_t)(row0w + row) * 128 + c4 * 4);
            unsigned long long pk = (unsigned long long)f2bf(v.x)
                | ((unsigned long long)f2bf(v.y) << 16)
                | ((unsigned long long)f2bf(v.z) << 32)
                | ((unsigned long long)f2bf(v.w) << 48);
            int byte = (row * 256 + c4 * 8) ^ ((row & 7) << 4);
            *(unsigned long long*)(regB + byte) = pk;
        }
        // ---- SE1: g1 = relu(feat @ se_wr + sebr) -> g1T in regA [128][16]
        {
            s16x8 a[4];
            #pragma unroll
            for (int ks = 0; ks < 4; ++ks)
                a[ks] = *(const s16x8*)(regB + ((r16 * 256 + ks * 64 + g * 16) ^ swz));
            f32x4 acc[8];
            #pragma unroll
            for (int n = 0; n < 8; ++n) acc[n] = (f32x4)0.f;
            #pragma unroll
            for (int n = 0; n < 8; ++n)
                #pragma unroll
                for (int ks = 0; ks < 4; ++ks) {
                    s16x8 b = *(const s16x8*)(sewrt + (n * 16 + r16) * 128 + ks * 32 + g * 8);
                    acc[n] = __builtin_amdgcn_mfma_f32_16x16x32_bf16(a[ks], b, acc[n], 0, 0, 0);
                }
            #pragma unroll
            for (int n = 0; n < 8; ++n) {
                float bias = sebr[n * 16 + r16];
                float e0 = fmaxf(acc[n][0] + bias, 0.f);
                float e1 = fmaxf(acc[n][1] + bias, 0.f);
                float e2 = fmaxf(acc[n][2] + bias, 0.f);
                float e3 = fmaxf(acc[n][3] + bias, 0.f);
                unsigned long long pk = (unsigned long long)f2bf(e0)
                    | ((unsigned long long)f2bf(e1) << 16)
                    | ((unsigned long long)f2bf(e2) << 32)
                    | ((unsigned long long)f2bf(e3) << 48);
                *(unsigned long long*)(regA + (n * 16 + r16) * 32 + g * 8) = pk;
            }
        }
        // ---- SE2: gacc = g1 @ se_we (tr reads from g1T)
        {
            LGKM0();                       // g1T writes landed
            s16x4 lo[4], hi[4];
            #pragma unroll
            for (int ks = 0; ks < 4; ++ks) {
                unsigned ad = bA + ks * 1024 + g * 128 + r16 * 2;
                lo[ks] = ds_tr16(ad);
                hi[ks] = ds_tr16(ad + 512);
            }
            LGKM0(); SBAR0();              // rule #18
            s16x8 a[4];
            #pragma unroll
            for (int ks = 0; ks < 4; ++ks)
                a[ks] = __builtin_shufflevector(lo[ks], hi[ks], 0, 1, 2, 3, 4, 5, 6, 7);
            #pragma unroll
            for (int n = 0; n < 8; ++n) gacc[n] = (f32x4)0.f;
            #pragma unroll
            for (int n = 0; n < 8; ++n)
                #pragma unroll
                for (int ks = 0; ks < 4; ++ks) {
                    s16x8 b = *(const s16x8*)(sewetp + (n * 16 + r16) * 128 + ks * 32 + g * 8);
                    gacc[n] = __builtin_amdgcn_mfma_f32_16x16x32_bf16(a[ks], b, gacc[n], 0, 0, 0);
                }
        }
    }

    // ---- sincos -> pe in regA [16][128] swizzled (overwrites g1T; safe)
    {
        const float p = (g < 2) ? py : px;
        s16x8 pv[4];
        #pragma unroll
        for (int kk = 0; kk < 16; ++kk) {
            int k = (g & 1) * 16 + kk;
            float ang = p * __builtin_exp2f((float)k * -0.41524101186092029f);
            float sn, cs;
            __sincosf(ang, &sn, &cs);
            pv[kk >> 2][(kk & 3) * 2]     = (short)f2bf(sn);
            pv[kk >> 2][(kk & 3) * 2 + 1] = (short)f2bf(cs);
        }
        #pragma unroll
        for (int c = 0; c < 4; ++c) {
            int byte = (r16 * 256 + g * 64 + c * 16) ^ swz;
            *(s16x8*)(regA + byte) = pv[c];
        }
    }

    f32x4 c2[8];
    #pragma unroll
    for (int n = 0; n < 8; ++n) c2[n] = (f32x4)0.f;

    s16x8 ape[4];
    #pragma unroll
    for (int ks = 0; ks < 4; ++ks)
        ape[ks] = *(const s16x8*)(regA + ((r16 * 256 + ks * 64 + g * 16) ^ swz));

    #pragma unroll
    for (int half = 0; half < 2; ++half) {
        // ---- G1 half: h = relu(pe @ W1[:,half*128..]) -> hT in regB [128][16]
        {
            f32x4 acc[8];
            #pragma unroll
            for (int n = 0; n < 8; ++n) acc[n] = (f32x4)0.f;
            #pragma unroll
            for (int n = 0; n < 8; ++n)
                #pragma unroll
                for (int ks = 0; ks < 4; ++ks) {
                    s16x8 b = *(const s16x8*)(w1t + (half * 128 + n * 16 + r16) * 128 + ks * 32 + g * 8);
                    acc[n] = __builtin_amdgcn_mfma_f32_16x16x32_bf16(ape[ks], b, acc[n], 0, 0, 0);
                }
            #pragma unroll
            for (int n = 0; n < 8; ++n) {
                float bias = b1[half * 128 + n * 16 + r16];
                float e0 = fmaxf(acc[n][0] + bias, 0.f);
                float e1 = fmaxf(acc[n][1] + bias, 0.f);
                float e2 = fmaxf(acc[n][2] + bias, 0.f);
                float e3 = fmaxf(acc[n][3] + bias, 0.f);
                unsigned long long pk = (unsigned long long)f2bf(e0)
                    | ((unsigned long long)f2bf(e1) << 16)
                    | ((unsigned long long)f2bf(e2) << 32)
                    | ((unsigned long long)f2bf(e3) << 48);
                *(unsigned long long*)(regB + (n * 16 + r16) * 32 + g * 8) = pk;
            }
        }
        // ---- G2 partial: c2 += h_half @ W2[half rows] (tr reads from hT)
        {
            LGKM0();                       // hT writes landed
            s16x4 lo[4], hi[4];
            #pragma unroll
            for (int ks = 0; ks < 4; ++ks) {
                unsigned ad = bB + ks * 1024 + g * 128 + r16 * 2;
                lo[ks] = ds_tr16(ad);
                hi[ks] = ds_tr16(ad + 512);
            }
            LGKM0(); SBAR0();              // rule #18
            s16x8 a[4];
            #pragma unroll
            for (int ks = 0; ks < 4; ++ks)
                a[ks] = __builtin_shufflevector(lo[ks], hi[ks], 0, 1, 2, 3, 4, 5, 6, 7);
            #pragma unroll
            for (int n = 0; n < 8; ++n)
                #pragma unroll
                for (int ks = 0; ks < 4; ++ks) {
                    s16x8 b = *(const s16x8*)(w2tp + (n * 16 + r16) * 256 + (half * 4 + ks) * 32 + g * 8);
                    c2[n] = __builtin_amdgcn_mfma_f32_16x16x32_bf16(a[ks], b, c2[n], 0, 0, 0);
                }
        }
    }

    // ---- store (bf16)
    #pragma unroll
    for (int n = 0; n < 8; ++n) {
        int col = n * 16 + r16;
        float b2v = b2[col];
        if (GATE) {
            float bev = sebe[col];
            #pragma unroll
            for (int r = 0; r < 4; ++r) {
                float gate = 1.0f / (1.0f + __expf(-(gacc[n][r] + bev)));
                outb[(size_t)(row0w + g * 4 + r) * 128 + col] = f2bf((c2[n][r] + b2v) * gate);
            }
        } else {
            #pragma unroll
            for (int r = 0; r < 4; ++r)
                outb[(size_t)(row0w + g * 4 + r) * 128 + col] = f2bf(c2[n][r] + b2v);
        }
    }
}

// ---------------------------------------------------------------------------
// attention: one wave per query; qpos/vposg bf16, feat f32.
// ---------------------------------------------------------------------------
__global__ __launch_bounds__(256) void attn_kernel(
    const float* __restrict__ ref_pts,
    const unsigned short* __restrict__ qpos,
    const unsigned short* __restrict__ vposg,
    const float* __restrict__ ctr_feat,
    float* __restrict__ out)
{
    const int lane = threadIdx.x & 63;
    const int qi   = blockIdx.x * 4 + (threadIdx.x >> 6);

    const int   b = (int)ref_pts[qi * 3 + 0];
    const float x = ref_pts[qi * 3 + 1];
    const float y = ref_pts[qi * 3 + 2];
    const int xi = (int)(floorf(x / 0.2f) * 0.5f + 128.0f);
    const int yi = (int)(floorf(y / 0.2f) * 0.5f + 128.0f);

    const unsigned qp = *(const unsigned*)(qpos + (size_t)qi * 128 + lane * 2);
    const float qx = bf2f((unsigned short)(qp & 0xffffu));
    const float qy = bf2f((unsigned short)(qp >> 16));

    float  sc[9];
    float2 fv[9];
    #pragma unroll
    for (int n = 0; n < 9; ++n) {
        const int nx = xi + n / 3 - 1;
        const int ny = yi + n % 3 - 1;
        const bool valid = ((unsigned)nx < 256u) && ((unsigned)ny < 256u);
        float  s = 0.f;
        float2 f = {0.f, 0.f};
        if (valid) {
            const int idx = (b << 16) + (nx << 8) + ny;
            const unsigned vp = *(const unsigned*)(vposg + (size_t)idx * 128 + lane * 2);
            f = *(const float2*)(ctr_feat + (size_t)idx * 128 + lane * 2);
            s = qx * bf2f((unsigned short)(vp & 0xffffu)) + qy * bf2f((unsigned short)(vp >> 16));
        }
        sc[n] = s;
        fv[n] = f;
    }

    #pragma unroll
    for (int off = 32; off > 0; off >>= 1) {
        #pragma unroll
        for (int n = 0; n < 9; ++n)
            sc[n] += __shfl_xor(sc[n], off, 64);
    }

    float m = -1e30f;
    #pragma unroll
    for (int n = 0; n < 9; ++n) {
        sc[n] *= SCALE_INV_SQRT_D;
        m = fmaxf(m, sc[n]);
    }
    float e[9], denom = 0.f;
    #pragma unroll
    for (int n = 0; n < 9; ++n) {
        e[n] = __expf(sc[n] - m);
        denom += e[n];
    }
    const float inv = 1.0f / denom;

    float2 o = {0.f, 0.f};
    #pragma unroll
    for (int n = 0; n < 9; ++n) {
        const float w = e[n] * inv;
        o.x += w * fv[n].x;
        o.y += w * fv[n].y;
    }
    *(float2*)(out + (size_t)qi * 128 + lane * 2) = o;
}

extern "C" void kernel_launch(void* const* d_in, const int* in_sizes, int n_in,
                              void* d_out, int out_size, void* d_ws, size_t ws_size,
                              hipStream_t stream) {
    const float* ref_pts  = (const float*)d_in[0];
    const int*   ctr_coor = (const int*)d_in[1];
    const float* ctr_feat = (const float*)d_in[2];
    const float* q_w1 = (const float*)d_in[3];
    const float* q_b1 = (const float*)d_in[4];
    const float* q_w2 = (const float*)d_in[5];
    const float* q_b2 = (const float*)d_in[6];
    const float* v_w1 = (const float*)d_in[7];
    const float* v_b1 = (const float*)d_in[8];
    const float* v_w2 = (const float*)d_in[9];
    const float* v_b2 = (const float*)d_in[10];
    const float* se_wr = (const float*)d_in[11];
    const float* se_br = (const float*)d_in[12];
    const float* se_we = (const float*)d_in[13];
    const float* se_be = (const float*)d_in[14];

    unsigned short* wbuf  = (unsigned short*)d_ws;                  // 163840
    unsigned short* vposg = wbuf + 163840;                          // V*128 bf16
    unsigned short* qposb = vposg + (size_t)NV * 128;               // Q*128 bf16

    const unsigned short* qw1t   = wbuf;
    const unsigned short* qw2tp  = wbuf + 32768;
    const unsigned short* vw1t   = wbuf + 65536;
    const unsigned short* vw2tp  = wbuf + 98304;
    const unsigned short* sewrt  = wbuf + 131072;
    const unsigned short* sewetp = wbuf + 147456;

    prep_kernel<<<640, 256, 0, stream>>>(q_w1, q_w2, v_w1, v_w2, se_wr, se_we, wbuf);

    mlp_kernel<false><<<NQ / 64, 256, 0, stream>>>(
        ref_pts, nullptr, nullptr,
        qw1t, q_b1, qw2tp, q_b2,
        nullptr, nullptr, nullptr, nullptr, qposb);

    mlp_kernel<true><<<NV / 64, 256, 0, stream>>>(
        nullptr, ctr_coor, ctr_feat,
        vw1t, v_b1, vw2tp, v_b2,
        sewrt, se_br, sewetp, se_be, vposg);

    attn_kernel<<<NQ / 4, 256, 0, stream>>>(
        ref_pts, qposb, vposg, ctr_feat, (float*)d_out);
}